// Round 9
// baseline (752.074 us; speedup 1.0000x reference)
//
#include <hip/hip_runtime.h>
#include <hip/hip_fp16.h>

#define NV 100000
#define NE 1600000

#define BM 64
#define BN 64
#define BK 16

#define SCAN_B 1024
#define NBLK ((NV + SCAN_B - 1) / SCAN_B)   // 98

typedef __attribute__((ext_vector_type(8))) _Float16 f16x8;
typedef __attribute__((ext_vector_type(4))) _Float16 f16x4;
typedef __attribute__((ext_vector_type(2))) _Float16 f16x2;
typedef __attribute__((ext_vector_type(4))) float f32x4;

// ---------------- degree histogram ----------------
__global__ void degree_count(const int* __restrict__ ef, int* __restrict__ deg, int n) {
    int i = blockIdx.x * blockDim.x + threadIdx.x;
    if (i < n) atomicAdd(&deg[ef[i]], 1);
}

// ---------------- block-level exclusive scan ----------------
__global__ __launch_bounds__(SCAN_B) void scan_block(const int* __restrict__ deg,
                                                     int* __restrict__ part,
                                                     int* __restrict__ bsum, int n) {
    __shared__ int tmp[SCAN_B];
    const int tid = threadIdx.x;
    const int gid = blockIdx.x * SCAN_B + tid;
    int v = (gid < n) ? deg[gid] : 0;
    tmp[tid] = v;
    __syncthreads();
    for (int off = 1; off < SCAN_B; off <<= 1) {
        int t = (tid >= off) ? tmp[tid - off] : 0;
        __syncthreads();
        tmp[tid] += t;
        __syncthreads();
    }
    if (gid < n) part[gid] = tmp[tid] - v;       // exclusive
    if (tid == SCAN_B - 1) bsum[blockIdx.x] = tmp[tid];
}

__global__ __launch_bounds__(128) void scan_top(int* __restrict__ bsum, int nb) {
    __shared__ int tmp[128];
    const int tid = threadIdx.x;
    int v = (tid < nb) ? bsum[tid] : 0;
    tmp[tid] = v;
    __syncthreads();
    for (int off = 1; off < 128; off <<= 1) {
        int t = (tid >= off) ? tmp[tid - off] : 0;
        __syncthreads();
        tmp[tid] += t;
        __syncthreads();
    }
    if (tid < nb) bsum[tid] = tmp[tid] - v;      // exclusive
}

__global__ __launch_bounds__(SCAN_B) void finalize_rowptr(int* __restrict__ rowptr,
                                                          const int* __restrict__ bsum,
                                                          const int* __restrict__ deg,
                                                          int* __restrict__ fill,
                                                          float* __restrict__ dinv, int n) {
    const int gid = blockIdx.x * SCAN_B + threadIdx.x;
    if (gid < n) {
        int r = rowptr[gid] + bsum[blockIdx.x];
        rowptr[gid] = r;
        fill[gid] = r;
        dinv[gid] = 1.0f / (float)deg[gid];
    }
    if (gid == 0) rowptr[n] = 2 * NE;
}

__global__ void fill_adj(const int* __restrict__ edges, int* __restrict__ fill,
                         int* __restrict__ adj, int nE) {
    int e = blockIdx.x * blockDim.x + threadIdx.x;
    if (e >= nE) return;
    const int a = edges[2 * e];
    const int b = edges[2 * e + 1];
    int pa = atomicAdd(&fill[a], 1); adj[pa] = b;
    int pb = atomicAdd(&fill[b], 1); adj[pb] = a;
}

// ---------------- weight convert+transpose: W[din][dout] fp32 -> WT[dout][din] fp16 ----------------
__global__ void convert_wt(const float* __restrict__ W, _Float16* __restrict__ WT,
                           int din, int dout) {
    int i = blockIdx.x * blockDim.x + threadIdx.x;
    if (i >= din * dout) return;
    const int k = i / dout, n = i % dout;
    WT[(size_t)n * din + k] = (_Float16)W[i];
}

// ---------------- MFMA dual GEMM, A in registers, WT fp16 pre-transposed ----------------
template <typename XT, int DIN, int NT>
__global__ __launch_bounds__(256) void gemm_dual_reg(
    const XT* __restrict__ X,
    const _Float16* __restrict__ WT0, const float* __restrict__ b0,
    const _Float16* __restrict__ WT1, const float* __restrict__ b1,
    _Float16* __restrict__ C0, _Float16* __restrict__ C1, int M)
{
    constexpr int DOUT = NT * 64;
    constexpr int NKS = DIN / 32;        // 32-K slices
    constexpr int NKC = DIN / 64;        // 64-K chunks
    constexpr int BST = 72;              // halfs per col (64 k + 8 pad)

    __shared__ _Float16 Bs[2][64 * BST];   // 18.4 KB

    const int tid = threadIdx.x;
    const int bm = blockIdx.x * 64;
    const int lane = tid & 63;
    const int wid = tid >> 6;
    const int wm = wid >> 1;
    const int wn = wid & 1;
    const int lr = lane & 15;
    const int lk = lane >> 4;

    // ---- A fragments -> registers ----
    f16x8 areg[NKS][2];
    #pragma unroll
    for (int ks = 0; ks < NKS; ++ks) {
        #pragma unroll
        for (int mf = 0; mf < 2; ++mf) {
            const int row = bm + wm * 32 + mf * 16 + lr;
            const int k = ks * 32 + lk * 8;
            f16x8 h = {};
            if (row < M) {
                if constexpr (sizeof(XT) == 4) {
                    const float4 v0 = *reinterpret_cast<const float4*>(&X[(size_t)row * DIN + k]);
                    const float4 v1 = *reinterpret_cast<const float4*>(&X[(size_t)row * DIN + k + 4]);
                    h[0] = (_Float16)v0.x; h[1] = (_Float16)v0.y;
                    h[2] = (_Float16)v0.z; h[3] = (_Float16)v0.w;
                    h[4] = (_Float16)v1.x; h[5] = (_Float16)v1.y;
                    h[6] = (_Float16)v1.z; h[7] = (_Float16)v1.w;
                } else {
                    h = *reinterpret_cast<const f16x8*>(&X[(size_t)row * DIN + k]);
                }
            }
            areg[ks][mf] = h;
        }
    }

    const int scol = tid >> 2;
    const int skb = (tid & 3) * 16;

    for (int nt = 0; nt < NT; ++nt) {
        f32x4 acc[2][2][2] = {};

        #pragma unroll
        for (int kc = 0; kc < NKC; ++kc) {
            {
                const size_t srcoff = (size_t)(nt * 64 + scol) * DIN + kc * 64 + skb;
                *reinterpret_cast<f16x8*>(&Bs[0][scol * BST + skb]) =
                    *reinterpret_cast<const f16x8*>(&WT0[srcoff]);
                *reinterpret_cast<f16x8*>(&Bs[0][scol * BST + skb + 8]) =
                    *reinterpret_cast<const f16x8*>(&WT0[srcoff + 8]);
                *reinterpret_cast<f16x8*>(&Bs[1][scol * BST + skb]) =
                    *reinterpret_cast<const f16x8*>(&WT1[srcoff]);
                *reinterpret_cast<f16x8*>(&Bs[1][scol * BST + skb + 8]) =
                    *reinterpret_cast<const f16x8*>(&WT1[srcoff + 8]);
            }
            __syncthreads();

            #pragma unroll
            for (int k2 = 0; k2 < 2; ++k2) {
                const int ks = kc * 2 + k2;
                f16x8 b[2][2];
                #pragma unroll
                for (int o = 0; o < 2; ++o)
                    #pragma unroll
                    for (int nf = 0; nf < 2; ++nf)
                        b[o][nf] = *reinterpret_cast<const f16x8*>(
                            &Bs[o][(wn * 32 + nf * 16 + lr) * BST + k2 * 32 + lk * 8]);
                #pragma unroll
                for (int o = 0; o < 2; ++o)
                    #pragma unroll
                    for (int mf = 0; mf < 2; ++mf)
                        #pragma unroll
                        for (int nf = 0; nf < 2; ++nf)
                            acc[o][mf][nf] = __builtin_amdgcn_mfma_f32_16x16x32_f16(
                                areg[ks][mf], b[o][nf], acc[o][mf][nf], 0, 0, 0);
            }
            __syncthreads();
        }

        #pragma unroll
        for (int mf = 0; mf < 2; ++mf) {
            #pragma unroll
            for (int reg = 0; reg < 4; ++reg) {
                const int row = bm + wm * 32 + mf * 16 + lk * 4 + reg;
                if (row >= M) continue;
                #pragma unroll
                for (int nf = 0; nf < 2; ++nf) {
                    const int c = nt * 64 + wn * 32 + nf * 16 + lr;
                    C0[(size_t)row * DOUT + c] = (_Float16)(acc[0][mf][nf][reg] + b0[c]);
                    C1[(size_t)row * DOUT + c] = (_Float16)(acc[1][mf][nf][reg] + b1[c]);
                }
            }
        }
    }
}

// ---------------- vector dual GEMM (layer 3 only: dout=3, fp16 X, fp32 out) ----------------
__global__ __launch_bounds__(256) void gemm_dual_bias_f32(
    const _Float16* __restrict__ X,
    const float* __restrict__ W0, const float* __restrict__ b0,
    const float* __restrict__ W1, const float* __restrict__ b1,
    float* __restrict__ C0, float* __restrict__ C1,
    int M, int din, int dout)
{
    __shared__ float As[BM][BK + 1];
    __shared__ float Bs0[BK][BN];
    __shared__ float Bs1[BK][BN];

    const int tid = threadIdx.x;
    const int bm = blockIdx.x * BM;
    const int bn = blockIdx.y * BN;
    const int tx = tid & 15;
    const int ty = tid >> 4;

    const int ar = tid >> 2;
    const int ac = (tid & 3) * 4;
    const int br = tid >> 4;
    const int bc = (tid & 15) * 4;

    float acc0[4][4] = {};
    float acc1[4][4] = {};

    for (int k0 = 0; k0 < din; k0 += BK) {
        {
            const int grow = bm + ar;
            if (grow < M) {
                const f16x4 v = *reinterpret_cast<const f16x4*>(&X[(size_t)grow * din + k0 + ac]);
                As[ar][ac + 0] = (float)v[0]; As[ar][ac + 1] = (float)v[1];
                As[ar][ac + 2] = (float)v[2]; As[ar][ac + 3] = (float)v[3];
            } else {
                As[ar][ac + 0] = 0.f; As[ar][ac + 1] = 0.f;
                As[ar][ac + 2] = 0.f; As[ar][ac + 3] = 0.f;
            }
        }
        {
            const int gk = k0 + br;
            const int gc = bn + bc;
            float4 v0, v1;
            v0.x = (gc + 0 < dout) ? W0[(size_t)gk * dout + gc + 0] : 0.f;
            v0.y = (gc + 1 < dout) ? W0[(size_t)gk * dout + gc + 1] : 0.f;
            v0.z = (gc + 2 < dout) ? W0[(size_t)gk * dout + gc + 2] : 0.f;
            v0.w = (gc + 3 < dout) ? W0[(size_t)gk * dout + gc + 3] : 0.f;
            v1.x = (gc + 0 < dout) ? W1[(size_t)gk * dout + gc + 0] : 0.f;
            v1.y = (gc + 1 < dout) ? W1[(size_t)gk * dout + gc + 1] : 0.f;
            v1.z = (gc + 2 < dout) ? W1[(size_t)gk * dout + gc + 2] : 0.f;
            v1.w = (gc + 3 < dout) ? W1[(size_t)gk * dout + gc + 3] : 0.f;
            *reinterpret_cast<float4*>(&Bs0[br][bc]) = v0;
            *reinterpret_cast<float4*>(&Bs1[br][bc]) = v1;
        }
        __syncthreads();

        #pragma unroll
        for (int kk = 0; kk < BK; ++kk) {
            const float a0 = As[ty * 4 + 0][kk];
            const float a1 = As[ty * 4 + 1][kk];
            const float a2 = As[ty * 4 + 2][kk];
            const float a3 = As[ty * 4 + 3][kk];
            const float4 p = *reinterpret_cast<const float4*>(&Bs0[kk][tx * 4]);
            const float4 q = *reinterpret_cast<const float4*>(&Bs1[kk][tx * 4]);
            acc0[0][0] += a0 * p.x; acc0[0][1] += a0 * p.y; acc0[0][2] += a0 * p.z; acc0[0][3] += a0 * p.w;
            acc0[1][0] += a1 * p.x; acc0[1][1] += a1 * p.y; acc0[1][2] += a1 * p.z; acc0[1][3] += a1 * p.w;
            acc0[2][0] += a2 * p.x; acc0[2][1] += a2 * p.y; acc0[2][2] += a2 * p.z; acc0[2][3] += a2 * p.w;
            acc0[3][0] += a3 * p.x; acc0[3][1] += a3 * p.y; acc0[3][2] += a3 * p.z; acc0[3][3] += a3 * p.w;
            acc1[0][0] += a0 * q.x; acc1[0][1] += a0 * q.y; acc1[0][2] += a0 * q.z; acc1[0][3] += a0 * q.w;
            acc1[1][0] += a1 * q.x; acc1[1][1] += a1 * q.y; acc1[1][2] += a1 * q.z; acc1[1][3] += a1 * q.w;
            acc1[2][0] += a2 * q.x; acc1[2][1] += a2 * q.y; acc1[2][2] += a2 * q.z; acc1[2][3] += a2 * q.w;
            acc1[3][0] += a3 * q.x; acc1[3][1] += a3 * q.y; acc1[3][2] += a3 * q.z; acc1[3][3] += a3 * q.w;
        }
        __syncthreads();
    }

    #pragma unroll
    for (int i = 0; i < 4; ++i) {
        const int row = bm + ty * 4 + i;
        if (row >= M) continue;
        #pragma unroll
        for (int j = 0; j < 4; ++j) {
            const int col = bn + tx * 4 + j;
            if (col < dout) {
                C0[(size_t)row * dout + col] = acc0[i][j] + b0[col];
                C1[(size_t)row * dout + col] = acc1[i][j] + b1[col];
            }
        }
    }
}

// ---------------- gathers: index-software-pipelined ----------------
// dout=192: 8 rows/iter; next iteration's 4 indices prefetched before row loads.
__global__ __launch_bounds__(256) void gather_d192_h(
    const _Float16* __restrict__ h0, const __half2* __restrict__ h1,
    const int* __restrict__ rowptr, const int* __restrict__ adj,
    const float* __restrict__ dinv, _Float16* __restrict__ out)
{
    const int v = blockIdx.x * 4 + (threadIdx.x >> 6);
    if (v >= NV) return;
    const int lane = threadIdx.x & 63;
    const int sub = lane >> 5;
    const int cu = (lane & 31) * 3;        // half2 column
    const int s = rowptr[v], e = rowptr[v + 1];

    float2 a0 = {0.f, 0.f}, a1 = {0.f, 0.f}, a2 = {0.f, 0.f};

    const int nblk = (e - s) >> 3;
    int j = s;
    int u0, u1, u2, u3;
    if (nblk > 0) {
        u0 = adj[s + 0 + sub]; u1 = adj[s + 2 + sub];
        u2 = adj[s + 4 + sub]; u3 = adj[s + 6 + sub];
    }
    for (int b = 0; b < nblk; ++b) {
        // prefetch next block's indices (clamped to a valid address; wave-uniform select)
        const int jn = (b + 1 < nblk) ? (j + 8) : s;
        const int n0 = adj[jn + 0 + sub];
        const int n1 = adj[jn + 2 + sub];
        const int n2 = adj[jn + 4 + sub];
        const int n3 = adj[jn + 6 + sub];

        const __half2* r0 = h1 + (size_t)u0 * 96 + cu;
        const __half2* r1 = h1 + (size_t)u1 * 96 + cu;
        const __half2* r2 = h1 + (size_t)u2 * 96 + cu;
        const __half2* r3 = h1 + (size_t)u3 * 96 + cu;
        const __half2 x00 = r0[0], x01 = r0[1], x02 = r0[2];
        const __half2 x10 = r1[0], x11 = r1[1], x12 = r1[2];
        const __half2 x20 = r2[0], x21 = r2[1], x22 = r2[2];
        const __half2 x30 = r3[0], x31 = r3[1], x32 = r3[2];
        float2 p;
        p = __half22float2(x00); a0.x += p.x; a0.y += p.y;
        p = __half22float2(x01); a1.x += p.x; a1.y += p.y;
        p = __half22float2(x02); a2.x += p.x; a2.y += p.y;
        p = __half22float2(x10); a0.x += p.x; a0.y += p.y;
        p = __half22float2(x11); a1.x += p.x; a1.y += p.y;
        p = __half22float2(x12); a2.x += p.x; a2.y += p.y;
        p = __half22float2(x20); a0.x += p.x; a0.y += p.y;
        p = __half22float2(x21); a1.x += p.x; a1.y += p.y;
        p = __half22float2(x22); a2.x += p.x; a2.y += p.y;
        p = __half22float2(x30); a0.x += p.x; a0.y += p.y;
        p = __half22float2(x31); a1.x += p.x; a1.y += p.y;
        p = __half22float2(x32); a2.x += p.x; a2.y += p.y;

        u0 = n0; u1 = n1; u2 = n2; u3 = n3;
        j += 8;
    }
    for (j = s + nblk * 8; j < e; j += 2) {
        const int jj = j + sub;
        if (jj < e) {
            const __half2* r = h1 + (size_t)adj[jj] * 96 + cu;
            float2 p;
            p = __half22float2(r[0]); a0.x += p.x; a0.y += p.y;
            p = __half22float2(r[1]); a1.x += p.x; a1.y += p.y;
            p = __half22float2(r[2]); a2.x += p.x; a2.y += p.y;
        }
    }

    a0.x += __shfl_xor(a0.x, 32); a0.y += __shfl_xor(a0.y, 32);
    a1.x += __shfl_xor(a1.x, 32); a1.y += __shfl_xor(a1.y, 32);
    a2.x += __shfl_xor(a2.x, 32); a2.y += __shfl_xor(a2.y, 32);

    if (sub == 0) {
        const float di = dinv[v];
        const size_t base = (size_t)v * 192 + (size_t)cu * 2;
        const f16x2 z0 = *reinterpret_cast<const f16x2*>(h0 + base + 0);
        const f16x2 z1 = *reinterpret_cast<const f16x2*>(h0 + base + 2);
        const f16x2 z2 = *reinterpret_cast<const f16x2*>(h0 + base + 4);
        f16x2 o0, o1, o2;
        o0[0] = (_Float16)fmaxf(((float)z0[0] + a0.x) * di, 0.f);
        o0[1] = (_Float16)fmaxf(((float)z0[1] + a0.y) * di, 0.f);
        o1[0] = (_Float16)fmaxf(((float)z1[0] + a1.x) * di, 0.f);
        o1[1] = (_Float16)fmaxf(((float)z1[1] + a1.y) * di, 0.f);
        o2[0] = (_Float16)fmaxf(((float)z2[0] + a2.x) * di, 0.f);
        o2[1] = (_Float16)fmaxf(((float)z2[1] + a2.y) * di, 0.f);
        *reinterpret_cast<f16x2*>(out + base + 0) = o0;
        *reinterpret_cast<f16x2*>(out + base + 2) = o1;
        *reinterpret_cast<f16x2*>(out + base + 4) = o2;
    }
}

// dout=128: 16 rows/iter; pipelined indices.
__global__ __launch_bounds__(256) void gather_d128_h(
    const _Float16* __restrict__ h0, const __half2* __restrict__ h1,
    const int* __restrict__ rowptr, const int* __restrict__ adj,
    const float* __restrict__ dinv, _Float16* __restrict__ out)
{
    const int v = blockIdx.x * 4 + (threadIdx.x >> 6);
    if (v >= NV) return;
    const int lane = threadIdx.x & 63;
    const int sub = lane >> 4;             // 0..3
    const int cu = (lane & 15) * 4;        // half2 column
    const int s = rowptr[v], e = rowptr[v + 1];

    float acc[8] = {};

    const int nblk = (e - s) >> 4;
    int j = s;
    int u0, u1, u2, u3;
    if (nblk > 0) {
        u0 = adj[s + 0 + sub]; u1 = adj[s + 4 + sub];
        u2 = adj[s + 8 + sub]; u3 = adj[s + 12 + sub];
    }
    for (int b = 0; b < nblk; ++b) {
        const int jn = (b + 1 < nblk) ? (j + 16) : s;
        const int n0 = adj[jn + 0 + sub];
        const int n1 = adj[jn + 4 + sub];
        const int n2 = adj[jn + 8 + sub];
        const int n3 = adj[jn + 12 + sub];

        const int4 w0 = *reinterpret_cast<const int4*>(h1 + (size_t)u0 * 64 + cu);
        const int4 w1 = *reinterpret_cast<const int4*>(h1 + (size_t)u1 * 64 + cu);
        const int4 w2 = *reinterpret_cast<const int4*>(h1 + (size_t)u2 * 64 + cu);
        const int4 w3 = *reinterpret_cast<const int4*>(h1 + (size_t)u3 * 64 + cu);
        #pragma unroll
        for (int t = 0; t < 4; ++t) {
            const float2 p0 = __half22float2(*(const __half2*)(&(&w0.x)[t]));
            const float2 p1 = __half22float2(*(const __half2*)(&(&w1.x)[t]));
            const float2 p2 = __half22float2(*(const __half2*)(&(&w2.x)[t]));
            const float2 p3 = __half22float2(*(const __half2*)(&(&w3.x)[t]));
            acc[2 * t + 0] += (p0.x + p1.x) + (p2.x + p3.x);
            acc[2 * t + 1] += (p0.y + p1.y) + (p2.y + p3.y);
        }

        u0 = n0; u1 = n1; u2 = n2; u3 = n3;
        j += 16;
    }
    for (j = s + nblk * 16; j < e; j += 4) {
        const int jj = j + sub;
        if (jj < e) {
            const int4 w0 = *reinterpret_cast<const int4*>(h1 + (size_t)adj[jj] * 64 + cu);
            #pragma unroll
            for (int t = 0; t < 4; ++t) {
                const float2 p = __half22float2(*(const __half2*)(&(&w0.x)[t]));
                acc[2 * t + 0] += p.x;
                acc[2 * t + 1] += p.y;
            }
        }
    }

    #pragma unroll
    for (int t = 0; t < 8; ++t) {
        acc[t] += __shfl_xor(acc[t], 16);
        acc[t] += __shfl_xor(acc[t], 32);
    }

    if (sub == 0) {
        const float di = dinv[v];
        const size_t base = (size_t)v * 128 + (size_t)cu * 2;
        const f16x8 z = *reinterpret_cast<const f16x8*>(h0 + base);
        f16x8 o;
        #pragma unroll
        for (int t = 0; t < 8; ++t)
            o[t] = (_Float16)fmaxf(((float)z[t] + acc[t]) * di, 0.f);
        *reinterpret_cast<f16x8*>(out + base) = o;
    }
}

// dout=64: 16 rows/iter; pipelined indices.
__global__ __launch_bounds__(256) void gather_d64_h(
    const _Float16* __restrict__ h0, const __half2* __restrict__ h1,
    const int* __restrict__ rowptr, const int* __restrict__ adj,
    const float* __restrict__ dinv, _Float16* __restrict__ out)
{
    const int v = blockIdx.x * 4 + (threadIdx.x >> 6);
    if (v >= NV) return;
    const int lane = threadIdx.x & 63;
    const int sub = lane >> 4;             // 0..3
    const int cu = (lane & 15) * 2;        // half2 column
    const int s = rowptr[v], e = rowptr[v + 1];

    float acc[4] = {};

    const int nblk = (e - s) >> 4;
    int j = s;
    int u0, u1, u2, u3;
    if (nblk > 0) {
        u0 = adj[s + 0 + sub]; u1 = adj[s + 4 + sub];
        u2 = adj[s + 8 + sub]; u3 = adj[s + 12 + sub];
    }
    for (int b = 0; b < nblk; ++b) {
        const int jn = (b + 1 < nblk) ? (j + 16) : s;
        const int n0 = adj[jn + 0 + sub];
        const int n1 = adj[jn + 4 + sub];
        const int n2 = adj[jn + 8 + sub];
        const int n3 = adj[jn + 12 + sub];

        const int2 w0 = *reinterpret_cast<const int2*>(h1 + (size_t)u0 * 32 + cu);
        const int2 w1 = *reinterpret_cast<const int2*>(h1 + (size_t)u1 * 32 + cu);
        const int2 w2 = *reinterpret_cast<const int2*>(h1 + (size_t)u2 * 32 + cu);
        const int2 w3 = *reinterpret_cast<const int2*>(h1 + (size_t)u3 * 32 + cu);
        #pragma unroll
        for (int t = 0; t < 2; ++t) {
            const float2 p0 = __half22float2(*(const __half2*)(&(&w0.x)[t]));
            const float2 p1 = __half22float2(*(const __half2*)(&(&w1.x)[t]));
            const float2 p2 = __half22float2(*(const __half2*)(&(&w2.x)[t]));
            const float2 p3 = __half22float2(*(const __half2*)(&(&w3.x)[t]));
            acc[2 * t + 0] += (p0.x + p1.x) + (p2.x + p3.x);
            acc[2 * t + 1] += (p0.y + p1.y) + (p2.y + p3.y);
        }

        u0 = n0; u1 = n1; u2 = n2; u3 = n3;
        j += 16;
    }
    for (j = s + nblk * 16; j < e; j += 4) {
        const int jj = j + sub;
        if (jj < e) {
            const int2 w0 = *reinterpret_cast<const int2*>(h1 + (size_t)adj[jj] * 32 + cu);
            #pragma unroll
            for (int t = 0; t < 2; ++t) {
                const float2 p = __half22float2(*(const __half2*)(&(&w0.x)[t]));
                acc[2 * t + 0] += p.x;
                acc[2 * t + 1] += p.y;
            }
        }
    }

    #pragma unroll
    for (int t = 0; t < 4; ++t) {
        acc[t] += __shfl_xor(acc[t], 16);
        acc[t] += __shfl_xor(acc[t], 32);
    }

    if (sub == 0) {
        const float di = dinv[v];
        const size_t base = (size_t)v * 64 + (size_t)cu * 2;
        const f16x4 z = *reinterpret_cast<const f16x4*>(h0 + base);
        f16x4 o;
        #pragma unroll
        for (int t = 0; t < 4; ++t)
            o[t] = (_Float16)fmaxf(((float)z[t] + acc[t]) * di, 0.f);
        *reinterpret_cast<f16x4*>(out + base) = o;
    }
}

__global__ __launch_bounds__(256) void gather_d3(
    const float* __restrict__ h0, const float* __restrict__ h1,
    const int* __restrict__ rowptr, const int* __restrict__ adj,
    const float* __restrict__ dinv, float* __restrict__ out)
{
    const int v = blockIdx.x * 4 + (threadIdx.x >> 6);
    if (v >= NV) return;
    const int lane = threadIdx.x & 63;
    const int s = rowptr[v], e = rowptr[v + 1];
    float a0 = 0.f, a1 = 0.f, a2 = 0.f;
    for (int j = s + lane; j < e; j += 64) {
        const float3 r = *reinterpret_cast<const float3*>(h1 + (size_t)adj[j] * 3);
        a0 += r.x; a1 += r.y; a2 += r.z;
    }
    #pragma unroll
    for (int off = 1; off < 64; off <<= 1) {
        a0 += __shfl_xor(a0, off);
        a1 += __shfl_xor(a1, off);
        a2 += __shfl_xor(a2, off);
    }
    if (lane == 0) {
        const float di = dinv[v];
        const size_t base = (size_t)v * 3;
        out[base + 0] = (h0[base + 0] + a0) * di;
        out[base + 1] = (h0[base + 1] + a1) * di;
        out[base + 2] = (h0[base + 2] + a2) * di;
    }
}

extern "C" void kernel_launch(void* const* d_in, const int* in_sizes, int n_in,
                              void* d_out, int out_size, void* d_ws, size_t ws_size,
                              hipStream_t stream) {
    const float* features = (const float*)d_in[0];
    const int*   edges    = (const int*)d_in[1];

    char* ws = (char*)d_ws;
    size_t off = 0;
    auto alloc = [&](size_t bytes) {
        void* p = ws + off;
        off = (off + bytes + 255) & ~(size_t)255;
        return p;
    };
    int*      deg    = (int*)alloc((size_t)NV * sizeof(int));
    float*    dinv   = (float*)alloc((size_t)NV * sizeof(float));
    int*      rowptr = (int*)alloc((size_t)(NV + 1) * sizeof(int));
    int*      fill   = (int*)alloc((size_t)NV * sizeof(int));
    int*      bsum   = (int*)alloc(256 * sizeof(int));
    int*      adj    = (int*)alloc((size_t)2 * NE * sizeof(int));
    _Float16* hC0    = (_Float16*)alloc((size_t)NV * 192 * sizeof(_Float16));
    _Float16* hC1    = (_Float16*)alloc((size_t)NV * 192 * sizeof(_Float16));
    _Float16* bufX1  = (_Float16*)alloc((size_t)NV * 192 * sizeof(_Float16));
    _Float16* bufX2  = (_Float16*)alloc((size_t)NV * 128 * sizeof(_Float16));
    float*    c0f    = (float*)alloc((size_t)NV * 3 * sizeof(float));
    float*    c1f    = (float*)alloc((size_t)NV * 3 * sizeof(float));
    _Float16* wt0_0  = (_Float16*)alloc((size_t)192 * 256 * sizeof(_Float16));
    _Float16* wt1_0  = (_Float16*)alloc((size_t)192 * 256 * sizeof(_Float16));
    _Float16* wt0_1  = (_Float16*)alloc((size_t)128 * 192 * sizeof(_Float16));
    _Float16* wt1_1  = (_Float16*)alloc((size_t)128 * 192 * sizeof(_Float16));
    _Float16* wt0_2  = (_Float16*)alloc((size_t)64 * 128 * sizeof(_Float16));
    _Float16* wt1_2  = (_Float16*)alloc((size_t)64 * 128 * sizeof(_Float16));

    // ---- CSR build ----
    hipMemsetAsync(deg, 0, (size_t)NV * sizeof(int), stream);
    degree_count<<<(2 * NE + 255) / 256, 256, 0, stream>>>(edges, deg, 2 * NE);
    scan_block<<<NBLK, SCAN_B, 0, stream>>>(deg, rowptr, bsum, NV);
    scan_top<<<1, 128, 0, stream>>>(bsum, NBLK);
    finalize_rowptr<<<NBLK, SCAN_B, 0, stream>>>(rowptr, bsum, deg, fill, dinv, NV);
    fill_adj<<<(NE + 255) / 256, 256, 0, stream>>>(edges, fill, adj, NE);

    // ---- weight convert/transpose (tiny) ----
    convert_wt<<<(256 * 192 + 255) / 256, 256, 0, stream>>>((const float*)d_in[2],  wt0_0, 256, 192);
    convert_wt<<<(256 * 192 + 255) / 256, 256, 0, stream>>>((const float*)d_in[4],  wt1_0, 256, 192);
    convert_wt<<<(192 * 128 + 255) / 256, 256, 0, stream>>>((const float*)d_in[6],  wt0_1, 192, 128);
    convert_wt<<<(192 * 128 + 255) / 256, 256, 0, stream>>>((const float*)d_in[8],  wt1_1, 192, 128);
    convert_wt<<<(128 * 64 + 255) / 256, 256, 0, stream>>>((const float*)d_in[10], wt0_2, 128, 64);
    convert_wt<<<(128 * 64 + 255) / 256, 256, 0, stream>>>((const float*)d_in[12], wt1_2, 128, 64);

    const int gatherGrid = (NV + 3) / 4;
    const int gemmGrid = (NV + 63) / 64;

    // ---- layer 0: 256 -> 192 ----
    gemm_dual_reg<float, 256, 3><<<gemmGrid, 256, 0, stream>>>(
        features, wt0_0, (const float*)d_in[3], wt1_0, (const float*)d_in[5],
        hC0, hC1, NV);
    gather_d192_h<<<gatherGrid, 256, 0, stream>>>(hC0, (const __half2*)hC1,
                                                  rowptr, adj, dinv, bufX1);

    // ---- layer 1: 192 -> 128 ----
    gemm_dual_reg<_Float16, 192, 2><<<gemmGrid, 256, 0, stream>>>(
        bufX1, wt0_1, (const float*)d_in[7], wt1_1, (const float*)d_in[9],
        hC0, hC1, NV);
    gather_d128_h<<<gatherGrid, 256, 0, stream>>>(hC0, (const __half2*)hC1,
                                                  rowptr, adj, dinv, bufX2);

    // ---- layer 2: 128 -> 64 ----
    gemm_dual_reg<_Float16, 128, 1><<<gemmGrid, 256, 0, stream>>>(
        bufX2, wt0_2, (const float*)d_in[11], wt1_2, (const float*)d_in[13],
        hC0, hC1, NV);
    gather_d64_h<<<gatherGrid, 256, 0, stream>>>(hC0, (const __half2*)hC1,
                                                 rowptr, adj, dinv, bufX1);

    // ---- layer 3: 64 -> 3 (fp32 epilogue path) ----
    {
        dim3 grid((NV + BM - 1) / BM, 1);
        gemm_dual_bias_f32<<<grid, 256, 0, stream>>>(
            bufX1,
            (const float*)d_in[14], (const float*)d_in[15],
            (const float*)d_in[16], (const float*)d_in[17],
            c0f, c1f, NV, 64, 3);
        gather_d3<<<gatherGrid, 256, 0, stream>>>(c0f, c1f, rowptr, adj, dinv, (float*)d_out);
    }
}

// Round 10
// 741.478 us; speedup vs baseline: 1.0143x; 1.0143x over previous
//
#include <hip/hip_runtime.h>
#include <hip/hip_fp16.h>

#define NV 100000
#define NE 1600000

#define BM 64
#define BN 64
#define BK 16

#define SCAN_B 1024
#define NBLK ((NV + SCAN_B - 1) / SCAN_B)   // 98

typedef __attribute__((ext_vector_type(8))) _Float16 f16x8;
typedef __attribute__((ext_vector_type(4))) _Float16 f16x4;
typedef __attribute__((ext_vector_type(2))) _Float16 f16x2;
typedef __attribute__((ext_vector_type(4))) float f32x4;

// ---------------- degree histogram ----------------
__global__ void degree_count(const int* __restrict__ ef, int* __restrict__ deg, int n) {
    int i = blockIdx.x * blockDim.x + threadIdx.x;
    if (i < n) atomicAdd(&deg[ef[i]], 1);
}

// ---------------- block-level exclusive scan ----------------
__global__ __launch_bounds__(SCAN_B) void scan_block(const int* __restrict__ deg,
                                                     int* __restrict__ part,
                                                     int* __restrict__ bsum, int n) {
    __shared__ int tmp[SCAN_B];
    const int tid = threadIdx.x;
    const int gid = blockIdx.x * SCAN_B + tid;
    int v = (gid < n) ? deg[gid] : 0;
    tmp[tid] = v;
    __syncthreads();
    for (int off = 1; off < SCAN_B; off <<= 1) {
        int t = (tid >= off) ? tmp[tid - off] : 0;
        __syncthreads();
        tmp[tid] += t;
        __syncthreads();
    }
    if (gid < n) part[gid] = tmp[tid] - v;       // exclusive
    if (tid == SCAN_B - 1) bsum[blockIdx.x] = tmp[tid];
}

__global__ __launch_bounds__(128) void scan_top(int* __restrict__ bsum, int nb) {
    __shared__ int tmp[128];
    const int tid = threadIdx.x;
    int v = (tid < nb) ? bsum[tid] : 0;
    tmp[tid] = v;
    __syncthreads();
    for (int off = 1; off < 128; off <<= 1) {
        int t = (tid >= off) ? tmp[tid - off] : 0;
        __syncthreads();
        tmp[tid] += t;
        __syncthreads();
    }
    if (tid < nb) bsum[tid] = tmp[tid] - v;      // exclusive
}

__global__ __launch_bounds__(SCAN_B) void finalize_rowptr(int* __restrict__ rowptr,
                                                          const int* __restrict__ bsum,
                                                          const int* __restrict__ deg,
                                                          int* __restrict__ fill,
                                                          float* __restrict__ dinv, int n) {
    const int gid = blockIdx.x * SCAN_B + threadIdx.x;
    if (gid < n) {
        int r = rowptr[gid] + bsum[blockIdx.x];
        rowptr[gid] = r;
        fill[gid] = r;
        dinv[gid] = 1.0f / (float)deg[gid];
    }
    if (gid == 0) rowptr[n] = 2 * NE;
}

__global__ void fill_adj(const int* __restrict__ edges, int* __restrict__ fill,
                         int* __restrict__ adj, int nE) {
    int e = blockIdx.x * blockDim.x + threadIdx.x;
    if (e >= nE) return;
    const int a = edges[2 * e];
    const int b = edges[2 * e + 1];
    int pa = atomicAdd(&fill[a], 1); adj[pa] = b;
    int pb = atomicAdd(&fill[b], 1); adj[pb] = a;
}

// ---------------- fused weight convert+transpose (all 6 matrices, 1 launch) ----------------
__global__ void convert_wt_all(
    const float* __restrict__ W00, const float* __restrict__ W10,
    const float* __restrict__ W01, const float* __restrict__ W11,
    const float* __restrict__ W02, const float* __restrict__ W12,
    _Float16* __restrict__ T00, _Float16* __restrict__ T10,
    _Float16* __restrict__ T01, _Float16* __restrict__ T11,
    _Float16* __restrict__ T02, _Float16* __restrict__ T12)
{
    const int n0 = 256 * 192, n1 = 192 * 128, n2 = 128 * 64;
    int r = blockIdx.x * blockDim.x + threadIdx.x;
    if (r < 2 * n0) {
        const float* W = (r < n0) ? W00 : W10;
        _Float16* T = (r < n0) ? T00 : T10;
        const int j = (r < n0) ? r : r - n0;
        const int k = j / 192, n = j % 192;
        T[(size_t)n * 256 + k] = (_Float16)W[j];
        return;
    }
    r -= 2 * n0;
    if (r < 2 * n1) {
        const float* W = (r < n1) ? W01 : W11;
        _Float16* T = (r < n1) ? T01 : T11;
        const int j = (r < n1) ? r : r - n1;
        const int k = j / 128, n = j % 128;
        T[(size_t)n * 192 + k] = (_Float16)W[j];
        return;
    }
    r -= 2 * n1;
    if (r < 2 * n2) {
        const float* W = (r < n2) ? W02 : W12;
        _Float16* T = (r < n2) ? T02 : T12;
        const int j = (r < n2) ? r : r - n2;
        const int k = j / 64, n = j % 64;
        T[(size_t)n * 128 + k] = (_Float16)W[j];
    }
}

// ---------------- MFMA dual GEMM, A in registers, WT fp16 pre-transposed ----------------
template <typename XT, int DIN, int NT>
__global__ __launch_bounds__(256) void gemm_dual_reg(
    const XT* __restrict__ X,
    const _Float16* __restrict__ WT0, const float* __restrict__ b0,
    const _Float16* __restrict__ WT1, const float* __restrict__ b1,
    _Float16* __restrict__ C0, _Float16* __restrict__ C1, int M)
{
    constexpr int DOUT = NT * 64;
    constexpr int NKS = DIN / 32;
    constexpr int NKC = DIN / 64;
    constexpr int BST = 72;

    __shared__ _Float16 Bs[2][64 * BST];

    const int tid = threadIdx.x;
    const int bm = blockIdx.x * 64;
    const int lane = tid & 63;
    const int wid = tid >> 6;
    const int wm = wid >> 1;
    const int wn = wid & 1;
    const int lr = lane & 15;
    const int lk = lane >> 4;

    f16x8 areg[NKS][2];
    #pragma unroll
    for (int ks = 0; ks < NKS; ++ks) {
        #pragma unroll
        for (int mf = 0; mf < 2; ++mf) {
            const int row = bm + wm * 32 + mf * 16 + lr;
            const int k = ks * 32 + lk * 8;
            f16x8 h = {};
            if (row < M) {
                if constexpr (sizeof(XT) == 4) {
                    const float4 v0 = *reinterpret_cast<const float4*>(&X[(size_t)row * DIN + k]);
                    const float4 v1 = *reinterpret_cast<const float4*>(&X[(size_t)row * DIN + k + 4]);
                    h[0] = (_Float16)v0.x; h[1] = (_Float16)v0.y;
                    h[2] = (_Float16)v0.z; h[3] = (_Float16)v0.w;
                    h[4] = (_Float16)v1.x; h[5] = (_Float16)v1.y;
                    h[6] = (_Float16)v1.z; h[7] = (_Float16)v1.w;
                } else {
                    h = *reinterpret_cast<const f16x8*>(&X[(size_t)row * DIN + k]);
                }
            }
            areg[ks][mf] = h;
        }
    }

    const int scol = tid >> 2;
    const int skb = (tid & 3) * 16;

    for (int nt = 0; nt < NT; ++nt) {
        f32x4 acc[2][2][2] = {};

        #pragma unroll
        for (int kc = 0; kc < NKC; ++kc) {
            {
                const size_t srcoff = (size_t)(nt * 64 + scol) * DIN + kc * 64 + skb;
                *reinterpret_cast<f16x8*>(&Bs[0][scol * BST + skb]) =
                    *reinterpret_cast<const f16x8*>(&WT0[srcoff]);
                *reinterpret_cast<f16x8*>(&Bs[0][scol * BST + skb + 8]) =
                    *reinterpret_cast<const f16x8*>(&WT0[srcoff + 8]);
                *reinterpret_cast<f16x8*>(&Bs[1][scol * BST + skb]) =
                    *reinterpret_cast<const f16x8*>(&WT1[srcoff]);
                *reinterpret_cast<f16x8*>(&Bs[1][scol * BST + skb + 8]) =
                    *reinterpret_cast<const f16x8*>(&WT1[srcoff + 8]);
            }
            __syncthreads();

            #pragma unroll
            for (int k2 = 0; k2 < 2; ++k2) {
                const int ks = kc * 2 + k2;
                f16x8 b[2][2];
                #pragma unroll
                for (int o = 0; o < 2; ++o)
                    #pragma unroll
                    for (int nf = 0; nf < 2; ++nf)
                        b[o][nf] = *reinterpret_cast<const f16x8*>(
                            &Bs[o][(wn * 32 + nf * 16 + lr) * BST + k2 * 32 + lk * 8]);
                #pragma unroll
                for (int o = 0; o < 2; ++o)
                    #pragma unroll
                    for (int mf = 0; mf < 2; ++mf)
                        #pragma unroll
                        for (int nf = 0; nf < 2; ++nf)
                            acc[o][mf][nf] = __builtin_amdgcn_mfma_f32_16x16x32_f16(
                                areg[ks][mf], b[o][nf], acc[o][mf][nf], 0, 0, 0);
            }
            __syncthreads();
        }

        #pragma unroll
        for (int mf = 0; mf < 2; ++mf) {
            #pragma unroll
            for (int reg = 0; reg < 4; ++reg) {
                const int row = bm + wm * 32 + mf * 16 + lk * 4 + reg;
                if (row >= M) continue;
                #pragma unroll
                for (int nf = 0; nf < 2; ++nf) {
                    const int c = nt * 64 + wn * 32 + nf * 16 + lr;
                    C0[(size_t)row * DOUT + c] = (_Float16)(acc[0][mf][nf][reg] + b0[c]);
                    C1[(size_t)row * DOUT + c] = (_Float16)(acc[1][mf][nf][reg] + b1[c]);
                }
            }
        }
    }
}

// ---------------- vector dual GEMM (layer 3 only: dout=3, fp16 X, fp32 out) ----------------
__global__ __launch_bounds__(256) void gemm_dual_bias_f32(
    const _Float16* __restrict__ X,
    const float* __restrict__ W0, const float* __restrict__ b0,
    const float* __restrict__ W1, const float* __restrict__ b1,
    float* __restrict__ C0, float* __restrict__ C1,
    int M, int din, int dout)
{
    __shared__ float As[BM][BK + 1];
    __shared__ float Bs0[BK][BN];
    __shared__ float Bs1[BK][BN];

    const int tid = threadIdx.x;
    const int bm = blockIdx.x * BM;
    const int bn = blockIdx.y * BN;
    const int tx = tid & 15;
    const int ty = tid >> 4;

    const int ar = tid >> 2;
    const int ac = (tid & 3) * 4;
    const int br = tid >> 4;
    const int bc = (tid & 15) * 4;

    float acc0[4][4] = {};
    float acc1[4][4] = {};

    for (int k0 = 0; k0 < din; k0 += BK) {
        {
            const int grow = bm + ar;
            if (grow < M) {
                const f16x4 v = *reinterpret_cast<const f16x4*>(&X[(size_t)grow * din + k0 + ac]);
                As[ar][ac + 0] = (float)v[0]; As[ar][ac + 1] = (float)v[1];
                As[ar][ac + 2] = (float)v[2]; As[ar][ac + 3] = (float)v[3];
            } else {
                As[ar][ac + 0] = 0.f; As[ar][ac + 1] = 0.f;
                As[ar][ac + 2] = 0.f; As[ar][ac + 3] = 0.f;
            }
        }
        {
            const int gk = k0 + br;
            const int gc = bn + bc;
            float4 v0, v1;
            v0.x = (gc + 0 < dout) ? W0[(size_t)gk * dout + gc + 0] : 0.f;
            v0.y = (gc + 1 < dout) ? W0[(size_t)gk * dout + gc + 1] : 0.f;
            v0.z = (gc + 2 < dout) ? W0[(size_t)gk * dout + gc + 2] : 0.f;
            v0.w = (gc + 3 < dout) ? W0[(size_t)gk * dout + gc + 3] : 0.f;
            v1.x = (gc + 0 < dout) ? W1[(size_t)gk * dout + gc + 0] : 0.f;
            v1.y = (gc + 1 < dout) ? W1[(size_t)gk * dout + gc + 1] : 0.f;
            v1.z = (gc + 2 < dout) ? W1[(size_t)gk * dout + gc + 2] : 0.f;
            v1.w = (gc + 3 < dout) ? W1[(size_t)gk * dout + gc + 3] : 0.f;
            *reinterpret_cast<float4*>(&Bs0[br][bc]) = v0;
            *reinterpret_cast<float4*>(&Bs1[br][bc]) = v1;
        }
        __syncthreads();

        #pragma unroll
        for (int kk = 0; kk < BK; ++kk) {
            const float a0 = As[ty * 4 + 0][kk];
            const float a1 = As[ty * 4 + 1][kk];
            const float a2 = As[ty * 4 + 2][kk];
            const float a3 = As[ty * 4 + 3][kk];
            const float4 p = *reinterpret_cast<const float4*>(&Bs0[kk][tx * 4]);
            const float4 q = *reinterpret_cast<const float4*>(&Bs1[kk][tx * 4]);
            acc0[0][0] += a0 * p.x; acc0[0][1] += a0 * p.y; acc0[0][2] += a0 * p.z; acc0[0][3] += a0 * p.w;
            acc0[1][0] += a1 * p.x; acc0[1][1] += a1 * p.y; acc0[1][2] += a1 * p.z; acc0[1][3] += a1 * p.w;
            acc0[2][0] += a2 * p.x; acc0[2][1] += a2 * p.y; acc0[2][2] += a2 * p.z; acc0[2][3] += a2 * p.w;
            acc0[3][0] += a3 * p.x; acc0[3][1] += a3 * p.y; acc0[3][2] += a3 * p.z; acc0[3][3] += a3 * p.w;
            acc1[0][0] += a0 * q.x; acc1[0][1] += a0 * q.y; acc1[0][2] += a0 * q.z; acc1[0][3] += a0 * q.w;
            acc1[1][0] += a1 * q.x; acc1[1][1] += a1 * q.y; acc1[1][2] += a1 * q.z; acc1[1][3] += a1 * q.w;
            acc1[2][0] += a2 * q.x; acc1[2][1] += a2 * q.y; acc1[2][2] += a2 * q.z; acc1[2][3] += a2 * q.w;
            acc1[3][0] += a3 * q.x; acc1[3][1] += a3 * q.y; acc1[3][2] += a3 * q.z; acc1[3][3] += a3 * q.w;
        }
        __syncthreads();
    }

    #pragma unroll
    for (int i = 0; i < 4; ++i) {
        const int row = bm + ty * 4 + i;
        if (row >= M) continue;
        #pragma unroll
        for (int j = 0; j < 4; ++j) {
            const int col = bn + tx * 4 + j;
            if (col < dout) {
                C0[(size_t)row * dout + col] = acc0[i][j] + b0[col];
                C1[(size_t)row * dout + col] = acc1[i][j] + b1[col];
            }
        }
    }
}

// ---------------- gathers: packed-fp16 accumulation ----------------
// dout=192: 2 rows/round (32 lanes x 3 f16x2), 4 rounds in flight; v_pk_add_f16 acc.
__global__ __launch_bounds__(256) void gather_d192_h(
    const _Float16* __restrict__ h0, const _Float16* __restrict__ h1,
    const int* __restrict__ rowptr, const int* __restrict__ adj,
    const float* __restrict__ dinv, _Float16* __restrict__ out)
{
    const int v = blockIdx.x * 4 + (threadIdx.x >> 6);
    if (v >= NV) return;
    const int lane = threadIdx.x & 63;
    const int sub = lane >> 5;
    const int cu = (lane & 31) * 3;        // f16x2 column
    const int s = rowptr[v], e = rowptr[v + 1];
    const f16x2* b1 = reinterpret_cast<const f16x2*>(h1);

    f16x2 a0 = {}, a1 = {}, a2 = {};

    int j = s;
    const int jend = s + ((e - s) & ~7);
    for (; j < jend; j += 8) {
        const f16x2* r0 = b1 + (size_t)adj[j + 0 + sub] * 96 + cu;
        const f16x2* r1 = b1 + (size_t)adj[j + 2 + sub] * 96 + cu;
        const f16x2* r2 = b1 + (size_t)adj[j + 4 + sub] * 96 + cu;
        const f16x2* r3 = b1 + (size_t)adj[j + 6 + sub] * 96 + cu;
        const f16x2 x00 = r0[0], x01 = r0[1], x02 = r0[2];
        const f16x2 x10 = r1[0], x11 = r1[1], x12 = r1[2];
        const f16x2 x20 = r2[0], x21 = r2[1], x22 = r2[2];
        const f16x2 x30 = r3[0], x31 = r3[1], x32 = r3[2];
        a0 += (x00 + x10) + (x20 + x30);
        a1 += (x01 + x11) + (x21 + x31);
        a2 += (x02 + x12) + (x22 + x32);
    }
    for (; j < e; j += 2) {
        const int jj = j + sub;
        if (jj < e) {
            const f16x2* r = b1 + (size_t)adj[jj] * 96 + cu;
            a0 += r[0]; a1 += r[1]; a2 += r[2];
        }
    }

    a0 += __builtin_bit_cast(f16x2, __shfl_xor(__builtin_bit_cast(int, a0), 32));
    a1 += __builtin_bit_cast(f16x2, __shfl_xor(__builtin_bit_cast(int, a1), 32));
    a2 += __builtin_bit_cast(f16x2, __shfl_xor(__builtin_bit_cast(int, a2), 32));

    if (sub == 0) {
        const float di = dinv[v];
        const size_t base = (size_t)v * 192 + (size_t)cu * 2;
        const f16x2 z0 = *reinterpret_cast<const f16x2*>(h0 + base + 0);
        const f16x2 z1 = *reinterpret_cast<const f16x2*>(h0 + base + 2);
        const f16x2 z2 = *reinterpret_cast<const f16x2*>(h0 + base + 4);
        f16x2 o0, o1, o2;
        o0[0] = (_Float16)fmaxf(((float)z0[0] + (float)a0[0]) * di, 0.f);
        o0[1] = (_Float16)fmaxf(((float)z0[1] + (float)a0[1]) * di, 0.f);
        o1[0] = (_Float16)fmaxf(((float)z1[0] + (float)a1[0]) * di, 0.f);
        o1[1] = (_Float16)fmaxf(((float)z1[1] + (float)a1[1]) * di, 0.f);
        o2[0] = (_Float16)fmaxf(((float)z2[0] + (float)a2[0]) * di, 0.f);
        o2[1] = (_Float16)fmaxf(((float)z2[1] + (float)a2[1]) * di, 0.f);
        *reinterpret_cast<f16x2*>(out + base + 0) = o0;
        *reinterpret_cast<f16x2*>(out + base + 2) = o1;
        *reinterpret_cast<f16x2*>(out + base + 4) = o2;
    }
}

// dout=128: 4 rows/round (16 lanes x f16x8), 4 rounds; pk-f16 acc.
__global__ __launch_bounds__(256) void gather_d128_h(
    const _Float16* __restrict__ h0, const _Float16* __restrict__ h1,
    const int* __restrict__ rowptr, const int* __restrict__ adj,
    const float* __restrict__ dinv, _Float16* __restrict__ out)
{
    const int v = blockIdx.x * 4 + (threadIdx.x >> 6);
    if (v >= NV) return;
    const int lane = threadIdx.x & 63;
    const int sub = lane >> 4;             // 0..3
    const int cuh = (lane & 15) * 8;       // half column
    const int s = rowptr[v], e = rowptr[v + 1];

    f16x8 acc = {};

    int j = s;
    const int jend = s + ((e - s) & ~15);
    for (; j < jend; j += 16) {
        const f16x8 w0 = *reinterpret_cast<const f16x8*>(h1 + (size_t)adj[j + 0 + sub] * 128 + cuh);
        const f16x8 w1 = *reinterpret_cast<const f16x8*>(h1 + (size_t)adj[j + 4 + sub] * 128 + cuh);
        const f16x8 w2 = *reinterpret_cast<const f16x8*>(h1 + (size_t)adj[j + 8 + sub] * 128 + cuh);
        const f16x8 w3 = *reinterpret_cast<const f16x8*>(h1 + (size_t)adj[j + 12 + sub] * 128 + cuh);
        acc += (w0 + w1) + (w2 + w3);
    }
    for (; j < e; j += 4) {
        const int jj = j + sub;
        if (jj < e)
            acc += *reinterpret_cast<const f16x8*>(h1 + (size_t)adj[jj] * 128 + cuh);
    }

    union U8 { f16x8 h; int i[4]; };
    #pragma unroll
    for (int offs = 16; offs <= 32; offs <<= 1) {
        U8 A, B;
        A.h = acc;
        #pragma unroll
        for (int t = 0; t < 4; ++t) B.i[t] = __shfl_xor(A.i[t], offs);
        acc = A.h + B.h;
    }

    if (sub == 0) {
        const float di = dinv[v];
        const size_t base = (size_t)v * 128 + cuh;
        const f16x8 z = *reinterpret_cast<const f16x8*>(h0 + base);
        f16x8 o;
        #pragma unroll
        for (int t = 0; t < 8; ++t)
            o[t] = (_Float16)fmaxf(((float)z[t] + (float)acc[t]) * di, 0.f);
        *reinterpret_cast<f16x8*>(out + base) = o;
    }
}

// dout=64: 4 rows/round (16 lanes x f16x4), 4 rounds; pk-f16 acc.
__global__ __launch_bounds__(256) void gather_d64_h(
    const _Float16* __restrict__ h0, const _Float16* __restrict__ h1,
    const int* __restrict__ rowptr, const int* __restrict__ adj,
    const float* __restrict__ dinv, _Float16* __restrict__ out)
{
    const int v = blockIdx.x * 4 + (threadIdx.x >> 6);
    if (v >= NV) return;
    const int lane = threadIdx.x & 63;
    const int sub = lane >> 4;             // 0..3
    const int cuh = (lane & 15) * 4;       // half column
    const int s = rowptr[v], e = rowptr[v + 1];

    f16x4 acc = {};

    int j = s;
    const int jend = s + ((e - s) & ~15);
    for (; j < jend; j += 16) {
        const f16x4 w0 = *reinterpret_cast<const f16x4*>(h1 + (size_t)adj[j + 0 + sub] * 64 + cuh);
        const f16x4 w1 = *reinterpret_cast<const f16x4*>(h1 + (size_t)adj[j + 4 + sub] * 64 + cuh);
        const f16x4 w2 = *reinterpret_cast<const f16x4*>(h1 + (size_t)adj[j + 8 + sub] * 64 + cuh);
        const f16x4 w3 = *reinterpret_cast<const f16x4*>(h1 + (size_t)adj[j + 12 + sub] * 64 + cuh);
        acc += (w0 + w1) + (w2 + w3);
    }
    for (; j < e; j += 4) {
        const int jj = j + sub;
        if (jj < e)
            acc += *reinterpret_cast<const f16x4*>(h1 + (size_t)adj[jj] * 64 + cuh);
    }

    union U4 { f16x4 h; int i[2]; };
    #pragma unroll
    for (int offs = 16; offs <= 32; offs <<= 1) {
        U4 A, B;
        A.h = acc;
        #pragma unroll
        for (int t = 0; t < 2; ++t) B.i[t] = __shfl_xor(A.i[t], offs);
        acc = A.h + B.h;
    }

    if (sub == 0) {
        const float di = dinv[v];
        const size_t base = (size_t)v * 64 + cuh;
        const f16x4 z = *reinterpret_cast<const f16x4*>(h0 + base);
        f16x4 o;
        #pragma unroll
        for (int t = 0; t < 4; ++t)
            o[t] = (_Float16)fmaxf(((float)z[t] + (float)acc[t]) * di, 0.f);
        *reinterpret_cast<f16x4*>(out + base) = o;
    }
}

__global__ __launch_bounds__(256) void gather_d3(
    const float* __restrict__ h0, const float* __restrict__ h1,
    const int* __restrict__ rowptr, const int* __restrict__ adj,
    const float* __restrict__ dinv, float* __restrict__ out)
{
    const int v = blockIdx.x * 4 + (threadIdx.x >> 6);
    if (v >= NV) return;
    const int lane = threadIdx.x & 63;
    const int s = rowptr[v], e = rowptr[v + 1];
    float a0 = 0.f, a1 = 0.f, a2 = 0.f;
    for (int j = s + lane; j < e; j += 64) {
        const float3 r = *reinterpret_cast<const float3*>(h1 + (size_t)adj[j] * 3);
        a0 += r.x; a1 += r.y; a2 += r.z;
    }
    #pragma unroll
    for (int off = 1; off < 64; off <<= 1) {
        a0 += __shfl_xor(a0, off);
        a1 += __shfl_xor(a1, off);
        a2 += __shfl_xor(a2, off);
    }
    if (lane == 0) {
        const float di = dinv[v];
        const size_t base = (size_t)v * 3;
        out[base + 0] = (h0[base + 0] + a0) * di;
        out[base + 1] = (h0[base + 1] + a1) * di;
        out[base + 2] = (h0[base + 2] + a2) * di;
    }
}

extern "C" void kernel_launch(void* const* d_in, const int* in_sizes, int n_in,
                              void* d_out, int out_size, void* d_ws, size_t ws_size,
                              hipStream_t stream) {
    const float* features = (const float*)d_in[0];
    const int*   edges    = (const int*)d_in[1];

    char* ws = (char*)d_ws;
    size_t off = 0;
    auto alloc = [&](size_t bytes) {
        void* p = ws + off;
        off = (off + bytes + 255) & ~(size_t)255;
        return p;
    };
    int*      deg    = (int*)alloc((size_t)NV * sizeof(int));
    float*    dinv   = (float*)alloc((size_t)NV * sizeof(float));
    int*      rowptr = (int*)alloc((size_t)(NV + 1) * sizeof(int));
    int*      fill   = (int*)alloc((size_t)NV * sizeof(int));
    int*      bsum   = (int*)alloc(256 * sizeof(int));
    int*      adj    = (int*)alloc((size_t)2 * NE * sizeof(int));
    _Float16* hC0    = (_Float16*)alloc((size_t)NV * 192 * sizeof(_Float16));
    _Float16* hC1    = (_Float16*)alloc((size_t)NV * 192 * sizeof(_Float16));
    _Float16* bufX1  = (_Float16*)alloc((size_t)NV * 192 * sizeof(_Float16));
    _Float16* bufX2  = (_Float16*)alloc((size_t)NV * 128 * sizeof(_Float16));
    float*    c0f    = (float*)alloc((size_t)NV * 3 * sizeof(float));
    float*    c1f    = (float*)alloc((size_t)NV * 3 * sizeof(float));
    _Float16* wt0_0  = (_Float16*)alloc((size_t)192 * 256 * sizeof(_Float16));
    _Float16* wt1_0  = (_Float16*)alloc((size_t)192 * 256 * sizeof(_Float16));
    _Float16* wt0_1  = (_Float16*)alloc((size_t)128 * 192 * sizeof(_Float16));
    _Float16* wt1_1  = (_Float16*)alloc((size_t)128 * 192 * sizeof(_Float16));
    _Float16* wt0_2  = (_Float16*)alloc((size_t)64 * 128 * sizeof(_Float16));
    _Float16* wt1_2  = (_Float16*)alloc((size_t)64 * 128 * sizeof(_Float16));

    // ---- CSR build ----
    hipMemsetAsync(deg, 0, (size_t)NV * sizeof(int), stream);
    degree_count<<<(2 * NE + 255) / 256, 256, 0, stream>>>(edges, deg, 2 * NE);
    scan_block<<<NBLK, SCAN_B, 0, stream>>>(deg, rowptr, bsum, NV);
    scan_top<<<1, 128, 0, stream>>>(bsum, NBLK);
    finalize_rowptr<<<NBLK, SCAN_B, 0, stream>>>(rowptr, bsum, deg, fill, dinv, NV);
    fill_adj<<<(NE + 255) / 256, 256, 0, stream>>>(edges, fill, adj, NE);

    // ---- fused weight convert/transpose ----
    {
        const int total = 2 * (256 * 192) + 2 * (192 * 128) + 2 * (128 * 64);
        convert_wt_all<<<(total + 255) / 256, 256, 0, stream>>>(
            (const float*)d_in[2], (const float*)d_in[4],
            (const float*)d_in[6], (const float*)d_in[8],
            (const float*)d_in[10], (const float*)d_in[12],
            wt0_0, wt1_0, wt0_1, wt1_1, wt0_2, wt1_2);
    }

    const int gatherGrid = (NV + 3) / 4;
    const int gemmGrid = (NV + 63) / 64;

    // ---- layer 0: 256 -> 192 ----
    gemm_dual_reg<float, 256, 3><<<gemmGrid, 256, 0, stream>>>(
        features, wt0_0, (const float*)d_in[3], wt1_0, (const float*)d_in[5],
        hC0, hC1, NV);
    gather_d192_h<<<gatherGrid, 256, 0, stream>>>(hC0, hC1, rowptr, adj, dinv, bufX1);

    // ---- layer 1: 192 -> 128 ----
    gemm_dual_reg<_Float16, 192, 2><<<gemmGrid, 256, 0, stream>>>(
        bufX1, wt0_1, (const float*)d_in[7], wt1_1, (const float*)d_in[9],
        hC0, hC1, NV);
    gather_d128_h<<<gatherGrid, 256, 0, stream>>>(hC0, hC1, rowptr, adj, dinv, bufX2);

    // ---- layer 2: 128 -> 64 ----
    gemm_dual_reg<_Float16, 128, 1><<<gemmGrid, 256, 0, stream>>>(
        bufX2, wt0_2, (const float*)d_in[11], wt1_2, (const float*)d_in[13],
        hC0, hC1, NV);
    gather_d64_h<<<gatherGrid, 256, 0, stream>>>(hC0, hC1, rowptr, adj, dinv, bufX1);

    // ---- layer 3: 64 -> 3 (fp32 epilogue path) ----
    {
        dim3 grid((NV + BM - 1) / BM, 1);
        gemm_dual_bias_f32<<<grid, 256, 0, stream>>>(
            bufX1,
            (const float*)d_in[14], (const float*)d_in[15],
            (const float*)d_in[16], (const float*)d_in[17],
            c0f, c1f, NV, 64, 3);
        gather_d3<<<gatherGrid, 256, 0, stream>>>(c0f, c1f, rowptr, adj, dinv, (float*)d_out);
    }
}